// Round 1
// baseline (467.066 us; speedup 1.0000x reference)
//
#include <hip/hip_runtime.h>
#include <hip/hip_bf16.h>
#include <cstdint>

#define DIM 1024
#define BATCH 4
#define SEQ 8192
#define M_TOTAL (BATCH * SEQ)   // 32768

#define CH 64               // number of chunks for the scan
#define CL (SEQ / CH)       // chunk length = 128

using bf16 = __hip_bfloat16;
typedef __attribute__((ext_vector_type(4))) float f32x4;
typedef __attribute__((ext_vector_type(8))) __bf16 bf16x8;

// ---------------------------------------------------------------------------
// fp32 -> bf16 conversion, float4 loads + bfloat162 stores
// ---------------------------------------------------------------------------
__global__ void f32_to_bf16_vec(const float* __restrict__ in,
                                bf16* __restrict__ out, long n4) {
    long i = blockIdx.x * (long)blockDim.x + threadIdx.x;
    if (i >= n4) return;
    const float4 v = ((const float4*)in)[i];
    __hip_bfloat162* o = (__hip_bfloat162*)(out + i * 4);
    o[0] = __float22bfloat162_rn(make_float2(v.x, v.y));
    o[1] = __float22bfloat162_rn(make_float2(v.z, v.w));
}

// ---------------------------------------------------------------------------
// C = A * B^T + bias.  A: [M][K] bf16 row-major, B: [N][K] bf16 row-major.
// 128x128 block tile, 4 waves of 64x64, mfma_f32_16x16x32_bf16,
// global_load_lds width=16 staging (m97 structure).
// OUT_MODE 0: bf16 output, OUT_MODE 1: fp32 output.
// ---------------------------------------------------------------------------
template <int OUT_MODE>
__global__ __launch_bounds__(256) void gemm_bt_kernel(
    const bf16* __restrict__ A, const bf16* __restrict__ B,
    const float* __restrict__ bias, void* __restrict__ C,
    int M, int N, int K) {
    __shared__ __align__(16) char lds[2 * 128 * 32 * 2];  // 8KB A + 8KB B
    char* ldsA = lds;
    char* ldsB = lds + 128 * 32 * 2;

    const int tid  = threadIdx.x;
    const int wave = tid >> 6;
    const int lane = tid & 63;
    const int bm = blockIdx.x;
    const int bn = blockIdx.y;
    const int wm = (wave >> 1) * 64;   // wave row offset in 128-tile
    const int wn = (wave & 1) * 64;    // wave col offset

    f32x4 acc[4][4];
#pragma unroll
    for (int i = 0; i < 4; i++)
#pragma unroll
        for (int j = 0; j < 4; j++) acc[i][j] = (f32x4){0.f, 0.f, 0.f, 0.f};

    const long arow_base = (long)bm * 128;
    const long brow_base = (long)bn * 128;

    const int fr_row = lane & 15;   // fragment row within 16x16 tile
    const int fr_kb  = lane >> 4;   // fragment k-block (0..3), 8 bf16 each

    for (int k0 = 0; k0 < K; k0 += 32) {
        // Stage A,B tiles: 128 rows x 32 cols bf16 = 8KB each.
        // Each thread issues 2 x 16B loads per tile; LDS layout is plain
        // row-major [row][32] (wave-uniform base + lane*16 constraint).
#pragma unroll
        for (int r = 0; r < 2; r++) {
            int c = tid + r * 256;          // 16B-chunk index, 0..511
            int row = c >> 2, kc = c & 3;
            const bf16* ga = A + (arow_base + row) * K + k0 + kc * 8;
            const bf16* gb = B + (brow_base + row) * K + k0 + kc * 8;
            __builtin_amdgcn_global_load_lds(
                (const __attribute__((address_space(1))) void*)ga,
                (__attribute__((address_space(3))) void*)(ldsA + c * 16),
                16, 0, 0);
            __builtin_amdgcn_global_load_lds(
                (const __attribute__((address_space(1))) void*)gb,
                (__attribute__((address_space(3))) void*)(ldsB + c * 16),
                16, 0, 0);
        }
        __syncthreads();

        bf16x8 af[4], bfg[4];
#pragma unroll
        for (int i = 0; i < 4; i++) {
            int rowA = wm + i * 16 + fr_row;
            af[i] = *(const bf16x8*)(ldsA + rowA * 64 + fr_kb * 16);
        }
#pragma unroll
        for (int j = 0; j < 4; j++) {
            int rowB = wn + j * 16 + fr_row;
            bfg[j] = *(const bf16x8*)(ldsB + rowB * 64 + fr_kb * 16);
        }
#pragma unroll
        for (int i = 0; i < 4; i++)
#pragma unroll
            for (int j = 0; j < 4; j++)
                acc[i][j] = __builtin_amdgcn_mfma_f32_16x16x32_bf16(
                    af[i], bfg[j], acc[i][j], 0, 0, 0);
        __syncthreads();
    }

    // Epilogue. C/D layout: m = (lane>>4)*4 + reg, n = lane&15 (m89-verified).
    const int crow = (lane >> 4) * 4;
    const int ccol = lane & 15;
#pragma unroll
    for (int i = 0; i < 4; i++) {
#pragma unroll
        for (int j = 0; j < 4; j++) {
            long mbase = (long)bm * 128 + wm + i * 16 + crow;
            int n = bn * 128 + wn + j * 16 + ccol;
            float bv = bias[n];
#pragma unroll
            for (int r = 0; r < 4; r++) {
                float v = acc[i][j][r] + bv;
                long idx = (mbase + r) * (long)N + n;
                if (OUT_MODE == 0)
                    ((bf16*)C)[idx] = __float2bfloat16(v);
                else
                    ((float*)C)[idx] = v;
            }
        }
    }
}

// ---------------------------------------------------------------------------
// Chunked diagonal linear scan: state_t = A_d * state_{t-1} + b_d * h_t
// ---------------------------------------------------------------------------
// Pass 1: per (batch, chunk) compute local final state (zero init).
__global__ __launch_bounds__(1024) void scan_pass1(
    const bf16* __restrict__ h, const float* __restrict__ a,
    const float* __restrict__ bcoef, float* __restrict__ S) {
    const int d = threadIdx.x;
    const int blk = blockIdx.x;
    const int b = blk / CH, c = blk % CH;
    const float Ad = 1.f / (1.f + expf(-a[d]));
    const float bd = bcoef[d];
    float s = 0.f;
    const bf16* hp = h + ((long)b * SEQ + (long)c * CL) * DIM + d;
#pragma unroll 4
    for (int t = 0; t < CL; t++)
        s = Ad * s + bd * __bfloat162float(hp[(long)t * DIM]);
    S[((long)b * CH + c) * DIM + d] = s;
}

// Pass 2: sequential combine across chunks; emit incoming state per chunk.
__global__ __launch_bounds__(1024) void scan_pass2(
    const float* __restrict__ S, const float* __restrict__ a,
    float* __restrict__ In) {
    const int d = threadIdx.x;
    const int b = blockIdx.x;
    const float Ad = 1.f / (1.f + expf(-a[d]));
    float Ap = Ad;                       // Ad^CL by repeated squaring, CL=128
#pragma unroll
    for (int i = 0; i < 7; i++) Ap *= Ap;
    float carry = 0.f;
    for (int c = 0; c < CH; c++) {
        In[((long)b * CH + c) * DIM + d] = carry;
        carry = Ap * carry + S[((long)b * CH + c) * DIM + d];
    }
}

// Pass 3: replay each chunk from its incoming state, write y over h in place.
__global__ __launch_bounds__(1024) void scan_pass3(
    bf16* __restrict__ h, const float* __restrict__ a,
    const float* __restrict__ bcoef, const float* __restrict__ In) {
    const int d = threadIdx.x;
    const int blk = blockIdx.x;
    const int b = blk / CH, c = blk % CH;
    const float Ad = 1.f / (1.f + expf(-a[d]));
    const float bd = bcoef[d];
    float s = In[((long)b * CH + c) * DIM + d];
    bf16* hp = h + ((long)b * SEQ + (long)c * CL) * DIM + d;
#pragma unroll 4
    for (int t = 0; t < CL; t++) {
        s = Ad * s + bd * __bfloat162float(hp[(long)t * DIM]);
        hp[(long)t * DIM] = __float2bfloat16(s);
    }
}

// ---------------------------------------------------------------------------
extern "C" void kernel_launch(void* const* d_in, const int* in_sizes, int n_in,
                              void* d_out, int out_size, void* d_ws,
                              size_t ws_size, hipStream_t stream) {
    const float* x     = (const float*)d_in[0];
    const float* w_in  = (const float*)d_in[1];
    const float* b_in  = (const float*)d_in[2];
    const float* a     = (const float*)d_in[3];
    const float* bcoef = (const float*)d_in[4];
    const float* w_out = (const float*)d_in[5];
    const float* b_out = (const float*)d_in[6];
    float* out = (float*)d_out;

    char* ws = (char*)d_ws;
    bf16* xb  = (bf16*)ws;  ws += (size_t)M_TOTAL * DIM * 2;   // 64 MB
    bf16* wib = (bf16*)ws;  ws += (size_t)DIM * DIM * 2;       // 2 MB
    bf16* wob = (bf16*)ws;  ws += (size_t)DIM * DIM * 2;       // 2 MB
    bf16* h   = (bf16*)ws;  ws += (size_t)M_TOTAL * DIM * 2;   // 64 MB (h then y)
    float* S  = (float*)ws; ws += (size_t)BATCH * CH * DIM * 4; // 1 MB
    float* In = (float*)ws; ws += (size_t)BATCH * CH * DIM * 4; // 1 MB

    // 1. fp32 -> bf16 conversions
    {
        long n4 = (long)M_TOTAL * DIM / 4;
        f32_to_bf16_vec<<<(int)((n4 + 255) / 256), 256, 0, stream>>>(x, xb, n4);
        long w4 = (long)DIM * DIM / 4;
        f32_to_bf16_vec<<<(int)((w4 + 255) / 256), 256, 0, stream>>>(w_in, wib, w4);
        f32_to_bf16_vec<<<(int)((w4 + 255) / 256), 256, 0, stream>>>(w_out, wob, w4);
    }

    dim3 gg(M_TOTAL / 128, DIM / 128);

    // 2. h = x @ w_in^T + b_in   (bf16 out)
    gemm_bt_kernel<0><<<gg, 256, 0, stream>>>(xb, wib, b_in, h, M_TOTAL, DIM, DIM);

    // 3. chunked scan (y overwrites h, bf16)
    scan_pass1<<<BATCH * CH, DIM, 0, stream>>>(h, a, bcoef, S);
    scan_pass2<<<BATCH, DIM, 0, stream>>>(S, a, In);
    scan_pass3<<<BATCH * CH, DIM, 0, stream>>>(h, a, bcoef, In);

    // 4. out = y @ w_out^T + b_out  (fp32 out)
    gemm_bt_kernel<1><<<gg, 256, 0, stream>>>(h, wob, b_out, out, M_TOTAL, DIM, DIM);
}

// Round 2
// 448.820 us; speedup vs baseline: 1.0407x; 1.0407x over previous
//
#include <hip/hip_runtime.h>
#include <hip/hip_bf16.h>
#include <cstdint>

#define DIM 1024
#define BATCH 4
#define SEQ 8192
#define M_TOTAL (BATCH * SEQ)   // 32768

#define CH 64               // number of chunks for the scan
#define CL (SEQ / CH)       // chunk length = 128

using bf16 = __hip_bfloat16;
typedef __attribute__((ext_vector_type(4))) float f32x4;
typedef __attribute__((ext_vector_type(8))) __bf16 bf16x8;

// ---------------------------------------------------------------------------
// fp32 -> bf16 conversion for x, w_in, w_out in ONE kernel (saves 2 launches)
// ---------------------------------------------------------------------------
__global__ void convert_all(const float* __restrict__ x, bf16* __restrict__ xb,
                            const float* __restrict__ w1, bf16* __restrict__ w1b,
                            const float* __restrict__ w2, bf16* __restrict__ w2b,
                            long n4x, long n4w) {
    long i = blockIdx.x * (long)blockDim.x + threadIdx.x;
    const float* in;
    bf16* out;
    long off;
    if (i < n4x)              { in = x;  out = xb;  off = i; }
    else if (i < n4x + n4w)   { in = w1; out = w1b; off = i - n4x; }
    else if (i < n4x + 2*n4w) { in = w2; out = w2b; off = i - n4x - n4w; }
    else return;
    const float4 v = ((const float4*)in)[off];
    __hip_bfloat162* o = (__hip_bfloat162*)(out + off * 4);
    o[0] = __float22bfloat162_rn(make_float2(v.x, v.y));
    o[1] = __float22bfloat162_rn(make_float2(v.z, v.w));
}

// ---------------------------------------------------------------------------
// C = A * B^T + bias.  A: [M][K] bf16 row-major, B: [N][K] bf16 row-major.
// 128x128 block tile, 4 waves of 64x64, mfma_f32_16x16x32_bf16.
// BK=64 (32 MFMA per barrier pair) + XOR-swizzled LDS chunk layout:
//   chunk(row, kc) = row*8 + (kc ^ (row & 7)); LDS dest stays linear
//   (global_load_lds wave-uniform-base constraint), the swizzle lives in
//   WHICH global 16B goes to which chunk. ds_read side: lanes 0-7 hit 8
//   distinct bank quads -> 2-way aliasing only (free per m136).
// OUT_MODE 0: bf16 output, OUT_MODE 1: fp32 output.
// ---------------------------------------------------------------------------
template <int OUT_MODE>
__global__ __launch_bounds__(256) void gemm_bt_kernel(
    const bf16* __restrict__ A, const bf16* __restrict__ B,
    const float* __restrict__ bias, void* __restrict__ C,
    int M, int N, int K) {
    __shared__ __align__(16) char lds[2 * 128 * 64 * 2];  // 16KB A + 16KB B
    char* ldsA = lds;
    char* ldsB = lds + 128 * 64 * 2;

    const int tid  = threadIdx.x;
    const int wave = tid >> 6;
    const int lane = tid & 63;
    const int bn = blockIdx.x;   // fast axis = N-tiles: A-tile reuse in L2
    const int bm = blockIdx.y;
    const int wm = (wave >> 1) * 64;   // wave row offset in 128-tile
    const int wn = (wave & 1) * 64;    // wave col offset

    f32x4 acc[4][4];
#pragma unroll
    for (int i = 0; i < 4; i++)
#pragma unroll
        for (int j = 0; j < 4; j++) acc[i][j] = (f32x4){0.f, 0.f, 0.f, 0.f};

    const long arow_base = (long)bm * 128;
    const long brow_base = (long)bn * 128;

    const int fr_row = lane & 15;   // fragment row within 16x16 tile
    const int fr_kb  = lane >> 4;   // fragment k-block (0..3), 8 bf16 each

    for (int k0 = 0; k0 < K; k0 += 64) {
        // Stage A,B tiles: 128 rows x 64 cols bf16 = 16KB each = 1024 chunks
        // of 16B. 256 threads -> 4 chunks per thread per matrix.
#pragma unroll
        for (int r = 0; r < 4; r++) {
            int c = tid + r * 256;             // chunk index, 0..1023
            int row = c >> 3;
            int kc = (c & 7) ^ (row & 7);      // un-swizzle to global kcol
            const bf16* ga = A + (arow_base + row) * (long)K + k0 + kc * 8;
            const bf16* gb = B + (brow_base + row) * (long)K + k0 + kc * 8;
            __builtin_amdgcn_global_load_lds(
                (const __attribute__((address_space(1))) void*)ga,
                (__attribute__((address_space(3))) void*)(ldsA + c * 16),
                16, 0, 0);
            __builtin_amdgcn_global_load_lds(
                (const __attribute__((address_space(1))) void*)gb,
                (__attribute__((address_space(3))) void*)(ldsB + c * 16),
                16, 0, 0);
        }
        __syncthreads();

#pragma unroll
        for (int ks = 0; ks < 2; ks++) {
            bf16x8 af[4], bfg[4];
#pragma unroll
            for (int i = 0; i < 4; i++) {
                int row = wm + i * 16 + fr_row;
                int cc = ks * 4 + fr_kb;
                int chunk = row * 8 + (cc ^ (row & 7));
                af[i] = *(const bf16x8*)(ldsA + chunk * 16);
            }
#pragma unroll
            for (int j = 0; j < 4; j++) {
                int row = wn + j * 16 + fr_row;
                int cc = ks * 4 + fr_kb;
                int chunk = row * 8 + (cc ^ (row & 7));
                bfg[j] = *(const bf16x8*)(ldsB + chunk * 16);
            }
#pragma unroll
            for (int i = 0; i < 4; i++)
#pragma unroll
                for (int j = 0; j < 4; j++)
                    acc[i][j] = __builtin_amdgcn_mfma_f32_16x16x32_bf16(
                        af[i], bfg[j], acc[i][j], 0, 0, 0);
        }
        __syncthreads();
    }

    // Epilogue. C/D layout: m = (lane>>4)*4 + reg, n = lane&15 (m89-verified).
    const int crow = (lane >> 4) * 4;
    const int ccol = lane & 15;
#pragma unroll
    for (int i = 0; i < 4; i++) {
#pragma unroll
        for (int j = 0; j < 4; j++) {
            long mbase = (long)bm * 128 + wm + i * 16 + crow;
            int n = bn * 128 + wn + j * 16 + ccol;
            float bv = bias[n];
#pragma unroll
            for (int r = 0; r < 4; r++) {
                float v = acc[i][j][r] + bv;
                long idx = (mbase + r) * (long)N + n;
                if (OUT_MODE == 0)
                    ((bf16*)C)[idx] = __float2bfloat16(v);
                else
                    ((float*)C)[idx] = v;
            }
        }
    }
}

// ---------------------------------------------------------------------------
// Chunked diagonal linear scan: state_t = A_d * state_{t-1} + b_d * h_t
// ---------------------------------------------------------------------------
// Pass 1: per (batch, chunk) compute local final state (zero init).
__global__ __launch_bounds__(1024) void scan_pass1(
    const bf16* __restrict__ h, const float* __restrict__ a,
    const float* __restrict__ bcoef, float* __restrict__ S) {
    const int d = threadIdx.x;
    const int blk = blockIdx.x;
    const int b = blk / CH, c = blk % CH;
    const float Ad = 1.f / (1.f + expf(-a[d]));
    const float bd = bcoef[d];
    float s = 0.f;
    const bf16* hp = h + ((long)b * SEQ + (long)c * CL) * DIM + d;
#pragma unroll 8
    for (int t = 0; t < CL; t++)
        s = Ad * s + bd * __bfloat162float(hp[(long)t * DIM]);
    S[((long)b * CH + c) * DIM + d] = s;
}

// Pass 3 (pass2 folded in): each block recomputes its incoming carry from the
// preceding chunks' S (batched x8 loads, L2-hot), then replays its chunk
// writing y over h in place.
__global__ __launch_bounds__(1024) void scan_pass3(
    bf16* __restrict__ h, const float* __restrict__ a,
    const float* __restrict__ bcoef, const float* __restrict__ S) {
    const int d = threadIdx.x;
    const int blk = blockIdx.x;
    const int b = blk / CH, c = blk % CH;
    const float Ad = 1.f / (1.f + expf(-a[d]));
    const float bd = bcoef[d];
    float Ap = Ad;                       // Ad^CL by repeated squaring, CL=128
#pragma unroll
    for (int i = 0; i < 7; i++) Ap *= Ap;

    // combine: carry after chunks [0, c)
    float carry = 0.f;
    const float* Sp = S + (long)b * CH * DIM + d;
    for (int i0 = 0; i0 < c; i0 += 8) {
        float sv[8];
        int nn = (c - i0 < 8) ? (c - i0) : 8;
#pragma unroll 8
        for (int j = 0; j < 8; j++)
            if (j < nn) sv[j] = Sp[(long)(i0 + j) * DIM];
#pragma unroll 8
        for (int j = 0; j < 8; j++)
            if (j < nn) carry = Ap * carry + sv[j];
    }

    float s = carry;
    bf16* hp = h + ((long)b * SEQ + (long)c * CL) * DIM + d;
#pragma unroll 8
    for (int t = 0; t < CL; t++) {
        s = Ad * s + bd * __bfloat162float(hp[(long)t * DIM]);
        hp[(long)t * DIM] = __float2bfloat16(s);
    }
}

// ---------------------------------------------------------------------------
extern "C" void kernel_launch(void* const* d_in, const int* in_sizes, int n_in,
                              void* d_out, int out_size, void* d_ws,
                              size_t ws_size, hipStream_t stream) {
    const float* x     = (const float*)d_in[0];
    const float* w_in  = (const float*)d_in[1];
    const float* b_in  = (const float*)d_in[2];
    const float* a     = (const float*)d_in[3];
    const float* bcoef = (const float*)d_in[4];
    const float* w_out = (const float*)d_in[5];
    const float* b_out = (const float*)d_in[6];
    float* out = (float*)d_out;

    char* ws = (char*)d_ws;
    bf16* xb  = (bf16*)ws;  ws += (size_t)M_TOTAL * DIM * 2;    // 64 MB
    bf16* wib = (bf16*)ws;  ws += (size_t)DIM * DIM * 2;        // 2 MB
    bf16* wob = (bf16*)ws;  ws += (size_t)DIM * DIM * 2;        // 2 MB
    bf16* h   = (bf16*)ws;  ws += (size_t)M_TOTAL * DIM * 2;    // 64 MB (h then y)
    float* S  = (float*)ws; ws += (size_t)BATCH * CH * DIM * 4; // 1 MB

    // 1. fp32 -> bf16 conversions (single kernel)
    {
        long n4x = (long)M_TOTAL * DIM / 4;
        long n4w = (long)DIM * DIM / 4;
        long total = n4x + 2 * n4w;
        convert_all<<<(int)((total + 255) / 256), 256, 0, stream>>>(
            x, xb, w_in, wib, w_out, wob, n4x, n4w);
    }

    dim3 gg(DIM / 128, M_TOTAL / 128);   // bn fast-varying for A-tile L2 reuse

    // 2. h = x @ w_in^T + b_in   (bf16 out)
    gemm_bt_kernel<0><<<gg, 256, 0, stream>>>(xb, wib, b_in, h, M_TOTAL, DIM, DIM);

    // 3. chunked scan (y overwrites h, bf16)
    scan_pass1<<<BATCH * CH, DIM, 0, stream>>>(h, a, bcoef, S);
    scan_pass3<<<BATCH * CH, DIM, 0, stream>>>(h, a, bcoef, S);

    // 4. out = y @ w_out^T + b_out  (fp32 out)
    gemm_bt_kernel<1><<<gg, 256, 0, stream>>>(h, wob, b_out, out, M_TOTAL, DIM, DIM);
}

// Round 3
// 412.987 us; speedup vs baseline: 1.1309x; 1.0868x over previous
//
#include <hip/hip_runtime.h>
#include <hip/hip_bf16.h>
#include <cstdint>

#define DIM 1024
#define BATCH 4
#define SEQ 8192
#define M_TOTAL (BATCH * SEQ)   // 32768

#define CH 64               // number of chunks for the scan
#define CL (SEQ / CH)       // chunk length = 128

using bf16 = __hip_bfloat16;
typedef __attribute__((ext_vector_type(16))) float f32x16;
typedef __attribute__((ext_vector_type(8))) __bf16 bf16x8;

// ---------------------------------------------------------------------------
// fp32 -> bf16 conversion for x, w_in, w_out in ONE kernel
// ---------------------------------------------------------------------------
__global__ void convert_all(const float* __restrict__ x, bf16* __restrict__ xb,
                            const float* __restrict__ w1, bf16* __restrict__ w1b,
                            const float* __restrict__ w2, bf16* __restrict__ w2b,
                            long n4x, long n4w) {
    long i = blockIdx.x * (long)blockDim.x + threadIdx.x;
    const float* in;
    bf16* out;
    long off;
    if (i < n4x)              { in = x;  out = xb;  off = i; }
    else if (i < n4x + n4w)   { in = w1; out = w1b; off = i - n4x; }
    else if (i < n4x + 2*n4w) { in = w2; out = w2b; off = i - n4x - n4w; }
    else return;
    const float4 v = ((const float4*)in)[off];
    __hip_bfloat162* o = (__hip_bfloat162*)(out + off * 4);
    o[0] = __float22bfloat162_rn(make_float2(v.x, v.y));
    o[1] = __float22bfloat162_rn(make_float2(v.z, v.w));
}

// ---------------------------------------------------------------------------
// C = A * B^T + bias.  A: [M][K] bf16 row-major, B: [N][K] bf16 row-major.
// 128x128 block tile, 4 waves of 64x64 = 2x2 of mfma_f32_32x32x16_bf16.
// BK=64, XOR-swizzled LDS 16B-chunk layout (round-2-verified, 0 conflicts):
//   chunk(row, kc) = row*8 + (kc ^ (row & 7)).
// XCD-aware block swizzle: L%8 = XCD (round-robin dispatch); each XCD owns a
// contiguous 32-tile bm range so every A-tile is fetched into exactly ONE
// per-XCD L2; bn fast within XCD for temporal A reuse.
// OUT_MODE 0: bf16 output, OUT_MODE 1: fp32 output.
// ---------------------------------------------------------------------------
template <int OUT_MODE>
__global__ __launch_bounds__(256) void gemm_bt_kernel(
    const bf16* __restrict__ A, const bf16* __restrict__ B,
    const float* __restrict__ bias, void* __restrict__ C,
    int M, int N, int K) {
    __shared__ __align__(16) char lds[2 * 128 * 64 * 2];  // 16KB A + 16KB B
    char* ldsA = lds;
    char* ldsB = lds + 128 * 64 * 2;

    const int tid  = threadIdx.x;
    const int wave = tid >> 6;
    const int lane = tid & 63;

    // XCD-aware swizzle. Grid = 2048 blocks = 256 bm x 8 bn.
    const int L   = blockIdx.x;
    const int xcd = L & 7;
    const int li  = L >> 3;            // 0..255 within XCD
    const int bm  = xcd * 32 + (li >> 3);
    const int bn  = li & 7;

    const int wm = (wave >> 1) * 64;   // wave row offset in 128-tile
    const int wn = (wave & 1) * 64;    // wave col offset

    f32x16 acc[2][2];
#pragma unroll
    for (int i = 0; i < 2; i++)
#pragma unroll
        for (int j = 0; j < 2; j++)
#pragma unroll
            for (int r = 0; r < 16; r++) acc[i][j][r] = 0.f;

    const long arow_base = (long)bm * 128;
    const long brow_base = (long)bn * 128;

    const int r31   = lane & 31;   // fragment row (m or n) within 32x32 tile
    const int khalf = lane >> 5;   // k half-block (0..1), 8 bf16 each

    for (int k0 = 0; k0 < K; k0 += 64) {
        // Stage A,B tiles: 128 rows x 64 cols bf16 = 16KB each = 1024 chunks
        // of 16B. 256 threads -> 4 chunks per thread per matrix.
#pragma unroll
        for (int r = 0; r < 4; r++) {
            int c = tid + r * 256;             // chunk index, 0..1023
            int row = c >> 3;
            int kc = (c & 7) ^ (row & 7);      // un-swizzle to global kcol
            const bf16* ga = A + (arow_base + row) * (long)K + k0 + kc * 8;
            const bf16* gb = B + (brow_base + row) * (long)K + k0 + kc * 8;
            __builtin_amdgcn_global_load_lds(
                (const __attribute__((address_space(1))) void*)ga,
                (__attribute__((address_space(3))) void*)(ldsA + c * 16),
                16, 0, 0);
            __builtin_amdgcn_global_load_lds(
                (const __attribute__((address_space(1))) void*)gb,
                (__attribute__((address_space(3))) void*)(ldsB + c * 16),
                16, 0, 0);
        }
        __syncthreads();

        // 4 k-steps of K=16. A-frag: m=lane&31, k=(lane>>5)*8+e.
#pragma unroll
        for (int s = 0; s < 4; s++) {
            const int kc = s * 2 + khalf;
            bf16x8 af[2], bfv[2];
#pragma unroll
            for (int i = 0; i < 2; i++) {
                int row = wm + i * 32 + r31;
                int chunk = row * 8 + (kc ^ (row & 7));
                af[i] = *(const bf16x8*)(ldsA + chunk * 16);
            }
#pragma unroll
            for (int j = 0; j < 2; j++) {
                int row = wn + j * 32 + r31;
                int chunk = row * 8 + (kc ^ (row & 7));
                bfv[j] = *(const bf16x8*)(ldsB + chunk * 16);
            }
#pragma unroll
            for (int i = 0; i < 2; i++)
#pragma unroll
                for (int j = 0; j < 2; j++)
                    acc[i][j] = __builtin_amdgcn_mfma_f32_32x32x16_bf16(
                        af[i], bfv[j], acc[i][j], 0, 0, 0);
        }
        __syncthreads();
    }

    // Epilogue. 32x32 C/D layout (m74/m101-verified):
    //   col = lane&31, row = (reg&3) + 8*(reg>>2) + 4*(lane>>5).
    const int ccol  = lane & 31;
    const int rbase = 4 * (lane >> 5);
#pragma unroll
    for (int i = 0; i < 2; i++) {
#pragma unroll
        for (int j = 0; j < 2; j++) {
            int n = bn * 128 + wn + j * 32 + ccol;
            float bv = bias[n];
#pragma unroll
            for (int r = 0; r < 16; r++) {
                int rowt = (r & 3) + 8 * (r >> 2) + rbase;
                long m = (long)bm * 128 + wm + i * 32 + rowt;
                float v = acc[i][j][r] + bv;
                long idx = m * (long)N + n;
                if (OUT_MODE == 0)
                    ((bf16*)C)[idx] = __float2bfloat16(v);
                else
                    ((float*)C)[idx] = v;
            }
        }
    }
}

// ---------------------------------------------------------------------------
// Chunked diagonal linear scan: state_t = A_d * state_{t-1} + b_d * h_t
// 2 channels per thread (bfloat162 loads/stores, 2 independent FMA chains).
// ---------------------------------------------------------------------------
__global__ __launch_bounds__(512) void scan_pass1(
    const bf16* __restrict__ h, const float* __restrict__ a,
    const float* __restrict__ bcoef, float* __restrict__ S) {
    const int d2 = threadIdx.x;            // channel pair 0..511
    const int blk = blockIdx.x;
    const int b = blk / CH, c = blk % CH;
    const float A0 = 1.f / (1.f + expf(-a[2 * d2]));
    const float A1 = 1.f / (1.f + expf(-a[2 * d2 + 1]));
    const float b0 = bcoef[2 * d2];
    const float b1 = bcoef[2 * d2 + 1];
    float s0 = 0.f, s1 = 0.f;
    const __hip_bfloat162* hp =
        (const __hip_bfloat162*)(h + ((long)b * SEQ + (long)c * CL) * DIM) + d2;
#pragma unroll 8
    for (int t = 0; t < CL; t++) {
        float2 v = __bfloat1622float2(hp[(long)t * (DIM / 2)]);
        s0 = A0 * s0 + b0 * v.x;
        s1 = A1 * s1 + b1 * v.y;
    }
    float2* Sp = (float2*)(S + ((long)b * CH + c) * DIM) + d2;
    *Sp = make_float2(s0, s1);
}

// Pass 3 (combine folded in): recompute incoming carry from preceding chunks'
// S (L2-hot), then replay the chunk writing y over h in place.
__global__ __launch_bounds__(512) void scan_pass3(
    bf16* __restrict__ h, const float* __restrict__ a,
    const float* __restrict__ bcoef, const float* __restrict__ S) {
    const int d2 = threadIdx.x;
    const int blk = blockIdx.x;
    const int b = blk / CH, c = blk % CH;
    const float A0 = 1.f / (1.f + expf(-a[2 * d2]));
    const float A1 = 1.f / (1.f + expf(-a[2 * d2 + 1]));
    const float b0 = bcoef[2 * d2];
    const float b1 = bcoef[2 * d2 + 1];
    float Ap0 = A0, Ap1 = A1;              // A^CL via repeated squaring, CL=128
#pragma unroll
    for (int i = 0; i < 7; i++) { Ap0 *= Ap0; Ap1 *= Ap1; }

    float c0 = 0.f, c1 = 0.f;
    const float2* Sp = (const float2*)(S + (long)b * CH * DIM) + d2;
    for (int i0 = 0; i0 < c; i0 += 8) {
        float2 sv[8];
        int nn = (c - i0 < 8) ? (c - i0) : 8;
#pragma unroll 8
        for (int j = 0; j < 8; j++)
            if (j < nn) sv[j] = Sp[(long)(i0 + j) * (DIM / 2)];
#pragma unroll 8
        for (int j = 0; j < 8; j++)
            if (j < nn) { c0 = Ap0 * c0 + sv[j].x; c1 = Ap1 * c1 + sv[j].y; }
    }

    float s0 = c0, s1 = c1;
    __hip_bfloat162* hp =
        (__hip_bfloat162*)(h + ((long)b * SEQ + (long)c * CL) * DIM) + d2;
#pragma unroll 8
    for (int t = 0; t < CL; t++) {
        float2 v = __bfloat1622float2(hp[(long)t * (DIM / 2)]);
        s0 = A0 * s0 + b0 * v.x;
        s1 = A1 * s1 + b1 * v.y;
        hp[(long)t * (DIM / 2)] = __float22bfloat162_rn(make_float2(s0, s1));
    }
}

// ---------------------------------------------------------------------------
extern "C" void kernel_launch(void* const* d_in, const int* in_sizes, int n_in,
                              void* d_out, int out_size, void* d_ws,
                              size_t ws_size, hipStream_t stream) {
    const float* x     = (const float*)d_in[0];
    const float* w_in  = (const float*)d_in[1];
    const float* b_in  = (const float*)d_in[2];
    const float* a     = (const float*)d_in[3];
    const float* bcoef = (const float*)d_in[4];
    const float* w_out = (const float*)d_in[5];
    const float* b_out = (const float*)d_in[6];
    float* out = (float*)d_out;

    char* ws = (char*)d_ws;
    bf16* xb  = (bf16*)ws;  ws += (size_t)M_TOTAL * DIM * 2;    // 64 MB
    bf16* wib = (bf16*)ws;  ws += (size_t)DIM * DIM * 2;        // 2 MB
    bf16* wob = (bf16*)ws;  ws += (size_t)DIM * DIM * 2;        // 2 MB
    bf16* h   = (bf16*)ws;  ws += (size_t)M_TOTAL * DIM * 2;    // 64 MB (h then y)
    float* S  = (float*)ws; ws += (size_t)BATCH * CH * DIM * 4; // 1 MB

    // 1. fp32 -> bf16 conversions (single kernel)
    {
        long n4x = (long)M_TOTAL * DIM / 4;
        long n4w = (long)DIM * DIM / 4;
        long total = n4x + 2 * n4w;
        convert_all<<<(int)((total + 255) / 256), 256, 0, stream>>>(
            x, xb, w_in, wib, w_out, wob, n4x, n4w);
    }

    const int nblocks = (M_TOTAL / 128) * (DIM / 128);  // 2048

    // 2. h = x @ w_in^T + b_in   (bf16 out)
    gemm_bt_kernel<0><<<nblocks, 256, 0, stream>>>(xb, wib, b_in, h,
                                                   M_TOTAL, DIM, DIM);

    // 3. chunked scan (y overwrites h, bf16)
    scan_pass1<<<BATCH * CH, 512, 0, stream>>>(h, a, bcoef, S);
    scan_pass3<<<BATCH * CH, 512, 0, stream>>>(h, a, bcoef, S);

    // 4. out = y @ w_out^T + b_out  (fp32 out)
    gemm_bt_kernel<1><<<nblocks, 256, 0, stream>>>(h, wob, b_out, out,
                                                   M_TOTAL, DIM, DIM);
}